// Round 4
// baseline (448.238 us; speedup 1.0000x reference)
//
#include <hip/hip_runtime.h>

#define N_NODES 8192
#define N_EDGES 262144
#define D 256
#define ADJ_WORDS 256     // 8192 bits per row / 32
#define MAX_DEG 128       // Poisson(33): P(deg>128) ~ 1e-40

typedef __attribute__((ext_vector_type(8))) short bf16x8;
typedef __attribute__((ext_vector_type(4))) float f32x4;

__device__ __forceinline__ short f2bf(float f) {
    unsigned u = __builtin_bit_cast(unsigned, f);
    u += 0x7fffu + ((u >> 16) & 1);   // round to nearest even
    return (short)(u >> 16);
}
__device__ __forceinline__ float bf2f(unsigned short u) {
    return __builtin_bit_cast(float, ((unsigned)u) << 16);
}

// ---------------- adjacency build: set-semantics bitmask + exact degree ----------------
__global__ void build_adj(const int* __restrict__ ei, unsigned* __restrict__ adj,
                          int* __restrict__ deg) {
    int i = blockIdx.x * blockDim.x + threadIdx.x;
    int r, c;
    if (i < N_EDGES) {
        r = ei[i];
        c = ei[N_EDGES + i];
    } else if (i < N_EDGES + N_NODES) {
        r = i - N_EDGES;          // self loop
        c = r;
    } else {
        return;
    }
    unsigned bit = 1u << (c & 31);
    unsigned old = atomicOr(&adj[r * ADJ_WORDS + (c >> 5)], bit);
    if (!(old & bit)) atomicAdd(&deg[r], 1);   // count only newly-set bits (set semantics)
}

// ---------------- deg -> dinv = deg^-0.5 ----------------
__global__ __launch_bounds__(256) void compute_dinv(const int* __restrict__ deg,
                                                    float* __restrict__ dinv) {
    int i = blockIdx.x * 256 + threadIdx.x;
    int d = deg[i];
    dinv[i] = d > 0 ? rsqrtf((float)d) : 0.0f;
}

// ------- bitmask -> compact neighbor list (+weight folded); tail blocks convert W to bf16 -------
__global__ __launch_bounds__(256) void build_nbrs(const unsigned* __restrict__ adj,
                                                  const float* __restrict__ dinv,
                                                  int* __restrict__ nbr_idx,
                                                  float* __restrict__ nbr_w,
                                                  const float* __restrict__ W1,
                                                  const float* __restrict__ W2,
                                                  const float* __restrict__ W3,
                                                  unsigned short* __restrict__ Wb1,
                                                  unsigned short* __restrict__ Wb2,
                                                  unsigned short* __restrict__ Wb3) {
    if (blockIdx.x >= N_NODES) {   // weight-conversion tail blocks (uniform per block)
        int i = (blockIdx.x - N_NODES) * 256 + threadIdx.x;
        int which = i >> 16, j = i & 65535;
        const float* src = which == 0 ? W1 : which == 1 ? W2 : W3;
        unsigned short* dst = which == 0 ? Wb1 : which == 1 ? Wb2 : Wb3;
        dst[j] = (unsigned short)f2bf(src[j]);
        return;
    }
    const int r = blockIdx.x;
    const int t = threadIdx.x;
    const int lane = t & 63, wave = t >> 6;
    unsigned m = adj[r * ADJ_WORDS + t];
    int cnt = __popc(m);
    int x = cnt;
    #pragma unroll
    for (int off = 1; off < 64; off <<= 1) {
        int v = __shfl_up(x, off, 64);
        if (lane >= off) x += v;
    }
    __shared__ int wtot[4];
    if (lane == 63) wtot[wave] = x;
    __syncthreads();
    int woff = 0;
    #pragma unroll
    for (int w = 0; w < 4; w++) woff += (w < wave) ? wtot[w] : 0;
    int base = woff + x - cnt;       // exclusive prefix
    const float dr = dinv[r];
    int* oi = nbr_idx + (size_t)r * MAX_DEG;
    float* ow = nbr_w + (size_t)r * MAX_DEG;
    while (m) {
        int b = __ffs(m) - 1;
        m &= m - 1;
        int c = (t << 5) + b;
        if (base < MAX_DEG) {
            oi[base] = c;
            ow[base] = dr * dinv[c];
        }
        base++;
    }
}

// ---------------- Hb(bf16) = X @ W^T + b  (MFMA 16x16x32 bf16) ----------------
// A = W (n rows), B = X (m cols): C/D col(lane&15)=m, row(q*4+reg)=n -> 8B packed stores
template <bool XF32>
__global__ __launch_bounds__(256) void gemm_mfma(const void* __restrict__ Xsrc,
                                                 const unsigned short* __restrict__ Wb,
                                                 const float* __restrict__ bias,
                                                 unsigned short* __restrict__ Hb) {
    const int bn = blockIdx.x * 64;           // output-channel tile
    const int bm = blockIdx.y * 128;          // node tile
    const int tid = threadIdx.x;
    const int wave = tid >> 6, lane = tid & 63;
    const int l16 = lane & 15, q = lane >> 4;
    const int mrow0 = bm + wave * 32;

    f32x4 acc[2][4];
    #pragma unroll
    for (int i = 0; i < 2; i++)
        #pragma unroll
        for (int j = 0; j < 4; j++) acc[i][j] = (f32x4){0.f, 0.f, 0.f, 0.f};

    for (int k0 = 0; k0 < D; k0 += 32) {
        const int kq = k0 + q * 8;
        bf16x8 xb[2];
        #pragma unroll
        for (int mf = 0; mf < 2; mf++) {
            const int m = mrow0 + mf * 16 + l16;
            if (XF32) {
                const float* xr = (const float*)Xsrc + (size_t)m * D + kq;
                float4 a = *(const float4*)xr;
                float4 b = *(const float4*)(xr + 4);
                float v[8] = {a.x, a.y, a.z, a.w, b.x, b.y, b.z, b.w};
                #pragma unroll
                for (int j = 0; j < 8; j++) xb[mf][j] = f2bf(v[j]);
            } else {
                xb[mf] = *(const bf16x8*)((const unsigned short*)Xsrc + (size_t)m * D + kq);
            }
        }
        #pragma unroll
        for (int nf = 0; nf < 4; nf++) {
            bf16x8 wa = *(const bf16x8*)(Wb + (size_t)(bn + nf * 16 + l16) * D + kq);
            #pragma unroll
            for (int mf = 0; mf < 2; mf++)
                acc[mf][nf] = __builtin_amdgcn_mfma_f32_16x16x32_bf16(wa, xb[mf], acc[mf][nf], 0, 0, 0);
        }
    }

    #pragma unroll
    for (int mf = 0; mf < 2; mf++) {
        const int m = mrow0 + mf * 16 + l16;
        #pragma unroll
        for (int nf = 0; nf < 4; nf++) {
            const int nb = bn + nf * 16 + q * 4;
            float4 b4 = *(const float4*)(bias + nb);
            short4 o;
            o.x = f2bf(acc[mf][nf][0] + b4.x);
            o.y = f2bf(acc[mf][nf][1] + b4.y);
            o.z = f2bf(acc[mf][nf][2] + b4.z);
            o.w = f2bf(acc[mf][nf][3] + b4.w);
            *(short4*)(Hb + (size_t)m * D + nb) = o;
        }
    }
}

// ------- aggregate + BN stats + device barrier + BN apply (+ReLU) in ONE kernel -------
// 256 blocks x 1024 threads: co-residency guaranteed (256 blocks <= 256 CUs at <=128 VGPR),
// so the arrive/spin barrier cannot deadlock.
template <bool LAST>
__global__ __launch_bounds__(1024, 4) void aggregate_fused(
        const int* __restrict__ nbr_idx, const float* __restrict__ nbr_w,
        const int* __restrict__ deg, const unsigned short* __restrict__ Hb,
        const float* __restrict__ g, const float* __restrict__ be,
        float* __restrict__ psum, float* __restrict__ psumsq, unsigned* __restrict__ counter,
        unsigned short* __restrict__ XbOut, float* __restrict__ FOut) {
    const int tid = threadIdx.x;
    const int wave = tid >> 6, lane = tid & 63;
    const int ch = lane * 4;

    float4 acc[2];
    #pragma unroll
    for (int i = 0; i < 2; i++) {
        const int r = blockIdx.x * 32 + wave * 2 + i;
        int dg = deg[r]; if (dg > MAX_DEG) dg = MAX_DEG;
        const int* idx = nbr_idx + (size_t)r * MAX_DEG;
        const float* wt = nbr_w + (size_t)r * MAX_DEG;
        float4 a = make_float4(0.f, 0.f, 0.f, 0.f);
        int j = 0;
        for (; j + 4 <= dg; j += 4) {
            int4 c4 = *(const int4*)(idx + j);
            float4 w4 = *(const float4*)(wt + j);
            ushort4 u0 = *(const ushort4*)(Hb + (size_t)c4.x * D + ch);
            ushort4 u1 = *(const ushort4*)(Hb + (size_t)c4.y * D + ch);
            ushort4 u2 = *(const ushort4*)(Hb + (size_t)c4.z * D + ch);
            ushort4 u3 = *(const ushort4*)(Hb + (size_t)c4.w * D + ch);
            a.x = fmaf(w4.x, bf2f(u0.x), a.x); a.y = fmaf(w4.x, bf2f(u0.y), a.y);
            a.z = fmaf(w4.x, bf2f(u0.z), a.z); a.w = fmaf(w4.x, bf2f(u0.w), a.w);
            a.x = fmaf(w4.y, bf2f(u1.x), a.x); a.y = fmaf(w4.y, bf2f(u1.y), a.y);
            a.z = fmaf(w4.y, bf2f(u1.z), a.z); a.w = fmaf(w4.y, bf2f(u1.w), a.w);
            a.x = fmaf(w4.z, bf2f(u2.x), a.x); a.y = fmaf(w4.z, bf2f(u2.y), a.y);
            a.z = fmaf(w4.z, bf2f(u2.z), a.z); a.w = fmaf(w4.z, bf2f(u2.w), a.w);
            a.x = fmaf(w4.w, bf2f(u3.x), a.x); a.y = fmaf(w4.w, bf2f(u3.y), a.y);
            a.z = fmaf(w4.w, bf2f(u3.z), a.z); a.w = fmaf(w4.w, bf2f(u3.w), a.w);
        }
        for (; j < dg; j++) {
            int c = idx[j];
            float w = wt[j];
            ushort4 u = *(const ushort4*)(Hb + (size_t)c * D + ch);
            a.x = fmaf(w, bf2f(u.x), a.x); a.y = fmaf(w, bf2f(u.y), a.y);
            a.z = fmaf(w, bf2f(u.z), a.z); a.w = fmaf(w, bf2f(u.w), a.w);
        }
        acc[i] = a;
    }

    // ---- block-level partial sums over channels ----
    __shared__ float ls[16][256];
    __shared__ float lss[16][256];
    {
        float s0 = acc[0].x + acc[1].x, s1 = acc[0].y + acc[1].y;
        float s2 = acc[0].z + acc[1].z, s3 = acc[0].w + acc[1].w;
        float q0 = acc[0].x * acc[0].x + acc[1].x * acc[1].x;
        float q1 = acc[0].y * acc[0].y + acc[1].y * acc[1].y;
        float q2 = acc[0].z * acc[0].z + acc[1].z * acc[1].z;
        float q3 = acc[0].w * acc[0].w + acc[1].w * acc[1].w;
        ls[wave][ch] = s0; ls[wave][ch + 1] = s1; ls[wave][ch + 2] = s2; ls[wave][ch + 3] = s3;
        lss[wave][ch] = q0; lss[wave][ch + 1] = q1; lss[wave][ch + 2] = q2; lss[wave][ch + 3] = q3;
    }
    __syncthreads();
    if (tid < 256) {
        float s = 0.f, q = 0.f;
        #pragma unroll
        for (int w = 0; w < 16; w++) { s += ls[w][tid]; q += lss[w][tid]; }
        atomicAdd(&psum[tid], s);
        atomicAdd(&psumsq[tid], q);
    }
    __threadfence();
    __syncthreads();

    // ---- device-scope arrive + spin (thread 0 only) ----
    if (tid == 0) {
        __hip_atomic_fetch_add(counter, 1u, __ATOMIC_RELEASE, __HIP_MEMORY_SCOPE_AGENT);
        while (__hip_atomic_load(counter, __ATOMIC_ACQUIRE, __HIP_MEMORY_SCOPE_AGENT) <
               (unsigned)gridDim.x) {
            __builtin_amdgcn_s_sleep(8);
        }
    }
    __syncthreads();

    // ---- finalize scale/shift (once per block, into LDS) ----
    __shared__ float ssc[256], ssh[256];
    if (tid < 256) {
        float s = __hip_atomic_load(&psum[tid], __ATOMIC_RELAXED, __HIP_MEMORY_SCOPE_AGENT);
        float q = __hip_atomic_load(&psumsq[tid], __ATOMIC_RELAXED, __HIP_MEMORY_SCOPE_AGENT);
        float mu = s * (1.0f / N_NODES);
        float var = q * (1.0f / N_NODES) - mu * mu;
        float rstd = rsqrtf(var + 1e-5f);
        float sc = g[tid] * rstd;
        ssc[tid] = sc;
        ssh[tid] = be[tid] - mu * sc;
    }
    __syncthreads();

    // ---- apply BN (+ReLU) and store ----
    float4 sc = *(const float4*)(ssc + ch);
    float4 sh = *(const float4*)(ssh + ch);
    #pragma unroll
    for (int i = 0; i < 2; i++) {
        const int r = blockIdx.x * 32 + wave * 2 + i;
        float v0 = fmaf(acc[i].x, sc.x, sh.x);
        float v1 = fmaf(acc[i].y, sc.y, sh.y);
        float v2 = fmaf(acc[i].z, sc.z, sh.z);
        float v3 = fmaf(acc[i].w, sc.w, sh.w);
        if (!LAST) {
            v0 = fmaxf(v0, 0.f); v1 = fmaxf(v1, 0.f);
            v2 = fmaxf(v2, 0.f); v3 = fmaxf(v3, 0.f);
            short4 o = {f2bf(v0), f2bf(v1), f2bf(v2), f2bf(v3)};
            *(short4*)(XbOut + (size_t)r * D + ch) = o;
        } else {
            float4 o = {v0, v1, v2, v3};
            *(float4*)(FOut + (size_t)r * D + ch) = o;
        }
    }
}

extern "C" void kernel_launch(void* const* d_in, const int* in_sizes, int n_in,
                              void* d_out, int out_size, void* d_ws, size_t ws_size,
                              hipStream_t stream) {
    const float* x  = (const float*)d_in[0];
    const int*   ei = (const int*)d_in[1];
    const float* W1 = (const float*)d_in[2];
    const float* b1 = (const float*)d_in[3];
    const float* W2 = (const float*)d_in[4];
    const float* b2 = (const float*)d_in[5];
    const float* W3 = (const float*)d_in[6];
    const float* b3 = (const float*)d_in[7];
    const float* g1 = (const float*)d_in[8];
    const float* be1 = (const float*)d_in[9];
    const float* g2 = (const float*)d_in[10];
    const float* be2 = (const float*)d_in[11];
    const float* g3 = (const float*)d_in[12];
    const float* be3 = (const float*)d_in[13];

    char* ws = (char*)d_ws;
    // [0, 8MB): adj bitmask; dead after build_nbrs -> reused as Hb (4MB) + Xb (4MB)
    unsigned*       adj  = (unsigned*)ws;
    unsigned short* Hb   = (unsigned short*)ws;                     // 4 MB
    unsigned short* Xb   = (unsigned short*)(ws + (4 << 20));       // 4 MB
    int*            deg  = (int*)(ws + (8 << 20));                  // 32 KB (zeroed)
    float*          psum = (float*)(ws + (8 << 20) + (32 << 10));   // 3*1KB (zeroed)
    float*          psq  = (float*)(ws + (8 << 20) + (36 << 10));   // 3*1KB (zeroed)
    unsigned*       cnt  = (unsigned*)(ws + (8 << 20) + (39 << 10));// 3*4B (zeroed)
    float*          dinv = (float*)(ws + (8 << 20) + (64 << 10));   // 32 KB
    unsigned short* Wb1  = (unsigned short*)(ws + (8 << 20) + (128 << 10));
    unsigned short* Wb2  = (unsigned short*)(ws + (8 << 20) + (256 << 10));
    unsigned short* Wb3  = (unsigned short*)(ws + (8 << 20) + (384 << 10));
    int*            nbr_idx = (int*)  (ws + (9 << 20));             // 4 MB
    float*          nbr_w   = (float*)(ws + (13 << 20));            // 4 MB

    // zero adj + deg + psum/psq/counters in one fill
    hipMemsetAsync(ws, 0, (8 << 20) + (40 << 10), stream);

    build_adj<<<(N_EDGES + N_NODES + 255) / 256, 256, 0, stream>>>(ei, adj, deg);
    compute_dinv<<<N_NODES / 256, 256, 0, stream>>>(deg, dinv);
    build_nbrs<<<N_NODES + 768, 256, 0, stream>>>(adj, dinv, nbr_idx, nbr_w,
                                                  W1, W2, W3, Wb1, Wb2, Wb3);

    dim3 ggrid(D / 64, N_NODES / 128);

    // Layer 1
    gemm_mfma<true><<<ggrid, 256, 0, stream>>>(x, Wb1, b1, Hb);
    aggregate_fused<false><<<256, 1024, 0, stream>>>(nbr_idx, nbr_w, deg, Hb, g1, be1,
                                                     psum + 0, psq + 0, cnt + 0, Xb, nullptr);
    // Layer 2
    gemm_mfma<false><<<ggrid, 256, 0, stream>>>(Xb, Wb2, b2, Hb);
    aggregate_fused<false><<<256, 1024, 0, stream>>>(nbr_idx, nbr_w, deg, Hb, g2, be2,
                                                     psum + 256, psq + 256, cnt + 1, Xb, nullptr);
    // Layer 3
    gemm_mfma<false><<<ggrid, 256, 0, stream>>>(Xb, Wb3, b3, Hb);
    aggregate_fused<true><<<256, 1024, 0, stream>>>(nbr_idx, nbr_w, deg, Hb, g3, be3,
                                                    psum + 512, psq + 512, cnt + 2, nullptr,
                                                    (float*)d_out);
}

// Round 5
// 340.184 us; speedup vs baseline: 1.3176x; 1.3176x over previous
//
#include <hip/hip_runtime.h>

#define N_NODES 8192
#define N_EDGES 262144
#define D 256
#define ADJ_WORDS 256     // 8192 bits per row / 32
#define MAX_DEG 128       // Poisson(33): P(deg>128) ~ 1e-40
#define AGG_BLOCKS 512    // 4 waves/block -> 2048 waves, 2 rows/wave/iter, 2 iters

typedef __attribute__((ext_vector_type(8))) short bf16x8;
typedef __attribute__((ext_vector_type(4))) float f32x4;

__device__ __forceinline__ short f2bf(float f) {
    unsigned u = __builtin_bit_cast(unsigned, f);
    u += 0x7fffu + ((u >> 16) & 1);   // round to nearest even
    return (short)(u >> 16);
}
__device__ __forceinline__ float bf2f(unsigned short u) {
    return __builtin_bit_cast(float, ((unsigned)u) << 16);
}

// ---------------- adjacency build: set-semantics bitmask + exact degree ----------------
__global__ void build_adj(const int* __restrict__ ei, unsigned* __restrict__ adj,
                          int* __restrict__ deg) {
    int i = blockIdx.x * blockDim.x + threadIdx.x;
    int r, c;
    if (i < N_EDGES) {
        r = ei[i];
        c = ei[N_EDGES + i];
    } else if (i < N_EDGES + N_NODES) {
        r = i - N_EDGES;          // self loop
        c = r;
    } else {
        return;
    }
    unsigned bit = 1u << (c & 31);
    unsigned old = atomicOr(&adj[r * ADJ_WORDS + (c >> 5)], bit);
    if (!(old & bit)) atomicAdd(&deg[r], 1);   // count only newly-set bits (set semantics)
}

// ---------------- deg -> dinv = deg^-0.5 ----------------
__global__ __launch_bounds__(256) void compute_dinv(const int* __restrict__ deg,
                                                    float* __restrict__ dinv) {
    int i = blockIdx.x * 256 + threadIdx.x;
    int d = deg[i];
    dinv[i] = d > 0 ? rsqrtf((float)d) : 0.0f;
}

// ------- bitmask -> packed neighbor list (u16 idx | bf16 weight); tail blocks: W->bf16 -------
__global__ __launch_bounds__(256) void build_nbrs(const unsigned* __restrict__ adj,
                                                  const float* __restrict__ dinv,
                                                  unsigned* __restrict__ nbr,
                                                  const float* __restrict__ W1,
                                                  const float* __restrict__ W2,
                                                  const float* __restrict__ W3,
                                                  unsigned short* __restrict__ Wb1,
                                                  unsigned short* __restrict__ Wb2,
                                                  unsigned short* __restrict__ Wb3) {
    if (blockIdx.x >= N_NODES) {   // weight-conversion tail blocks
        int i = (blockIdx.x - N_NODES) * 256 + threadIdx.x;
        int which = i >> 16, j = i & 65535;
        const float* src = which == 0 ? W1 : which == 1 ? W2 : W3;
        unsigned short* dst = which == 0 ? Wb1 : which == 1 ? Wb2 : Wb3;
        dst[j] = (unsigned short)f2bf(src[j]);
        return;
    }
    const int r = blockIdx.x;
    const int t = threadIdx.x;
    const int lane = t & 63, wave = t >> 6;
    unsigned m = adj[r * ADJ_WORDS + t];
    int cnt = __popc(m);
    int x = cnt;
    #pragma unroll
    for (int off = 1; off < 64; off <<= 1) {
        int v = __shfl_up(x, off, 64);
        if (lane >= off) x += v;
    }
    __shared__ int wtot[4];
    if (lane == 63) wtot[wave] = x;
    __syncthreads();
    int woff = 0;
    #pragma unroll
    for (int w = 0; w < 4; w++) woff += (w < wave) ? wtot[w] : 0;
    int base = woff + x - cnt;       // exclusive prefix
    const float dr = dinv[r];
    unsigned* on = nbr + (size_t)r * MAX_DEG;
    while (m) {
        int b = __ffs(m) - 1;
        m &= m - 1;
        int c = (t << 5) + b;
        if (base < MAX_DEG) {
            unsigned wb = (unsigned)(unsigned short)f2bf(dr * dinv[c]);
            on[base] = (unsigned)c | (wb << 16);
        }
        base++;
    }
}

// ---------------- Hb(bf16) = bnapply(Xsrc fp32) @ W^T + b  (MFMA 16x16x32 bf16) ----------------
// A = W (n rows), B = X (m cols): C/D col(lane&15)=m, row(q*4+reg)=n -> 8B packed bf16 store
template <bool APPLY, bool RELU>
__global__ __launch_bounds__(256) void gemm_mfma(const float* __restrict__ Xsrc,
                                                 const float* __restrict__ scale,
                                                 const float* __restrict__ shift,
                                                 const unsigned short* __restrict__ Wb,
                                                 const float* __restrict__ bias,
                                                 unsigned short* __restrict__ Hb) {
    const int bn = blockIdx.x * 64;           // output-channel tile
    const int bm = blockIdx.y * 128;          // node tile
    const int tid = threadIdx.x;
    const int wave = tid >> 6, lane = tid & 63;
    const int l16 = lane & 15, q = lane >> 4;
    const int mrow0 = bm + wave * 32;

    f32x4 acc[2][4];
    #pragma unroll
    for (int i = 0; i < 2; i++)
        #pragma unroll
        for (int j = 0; j < 4; j++) acc[i][j] = (f32x4){0.f, 0.f, 0.f, 0.f};

    for (int k0 = 0; k0 < D; k0 += 32) {
        const int kq = k0 + q * 8;
        bf16x8 xb[2];
        float4 sc0, sc1, sh0, sh1;
        if (APPLY) {
            sc0 = *(const float4*)(scale + kq);
            sc1 = *(const float4*)(scale + kq + 4);
            sh0 = *(const float4*)(shift + kq);
            sh1 = *(const float4*)(shift + kq + 4);
        }
        #pragma unroll
        for (int mf = 0; mf < 2; mf++) {
            const float* xr = Xsrc + (size_t)(mrow0 + mf * 16 + l16) * D + kq;
            float4 a = *(const float4*)xr;
            float4 b = *(const float4*)(xr + 4);
            float v[8] = {a.x, a.y, a.z, a.w, b.x, b.y, b.z, b.w};
            if (APPLY) {
                float sc[8] = {sc0.x, sc0.y, sc0.z, sc0.w, sc1.x, sc1.y, sc1.z, sc1.w};
                float sh[8] = {sh0.x, sh0.y, sh0.z, sh0.w, sh1.x, sh1.y, sh1.z, sh1.w};
                #pragma unroll
                for (int j = 0; j < 8; j++) {
                    v[j] = fmaf(v[j], sc[j], sh[j]);
                    if (RELU) v[j] = fmaxf(v[j], 0.0f);
                }
            }
            #pragma unroll
            for (int j = 0; j < 8; j++) xb[mf][j] = f2bf(v[j]);
        }
        #pragma unroll
        for (int nf = 0; nf < 4; nf++) {
            bf16x8 wa = *(const bf16x8*)(Wb + (size_t)(bn + nf * 16 + l16) * D + kq);
            #pragma unroll
            for (int mf = 0; mf < 2; mf++)
                acc[mf][nf] = __builtin_amdgcn_mfma_f32_16x16x32_bf16(wa, xb[mf], acc[mf][nf], 0, 0, 0);
        }
    }

    #pragma unroll
    for (int mf = 0; mf < 2; mf++) {
        const int m = mrow0 + mf * 16 + l16;
        #pragma unroll
        for (int nf = 0; nf < 4; nf++) {
            const int nb = bn + nf * 16 + q * 4;
            float4 b4 = *(const float4*)(bias + nb);
            short4 o;
            o.x = f2bf(acc[mf][nf][0] + b4.x);
            o.y = f2bf(acc[mf][nf][1] + b4.y);
            o.z = f2bf(acc[mf][nf][2] + b4.z);
            o.w = f2bf(acc[mf][nf][3] + b4.w);
            *(short4*)(Hb + (size_t)m * D + nb) = o;
        }
    }
}

// ------- G[r,:] = sum_j w * Hb[idx,:]  (packed nbrs, 2 rows/wave interleaved, 8-wide MLP) -------
__global__ __launch_bounds__(256) void aggregate_bf16(const unsigned* __restrict__ nbr,
                                                      const int* __restrict__ deg,
                                                      const unsigned short* __restrict__ Hb,
                                                      float* __restrict__ G,
                                                      float* __restrict__ psum,
                                                      float* __restrict__ psumsq) {
    const int wave = threadIdx.x >> 6;
    const int lane = threadIdx.x & 63;
    const int ch = lane * 4;
    const int wid = blockIdx.x * 4 + wave;      // 0..2047
    float sp[4] = {0.f, 0.f, 0.f, 0.f}, ssp[4] = {0.f, 0.f, 0.f, 0.f};

    for (int r0 = wid * 2; r0 < N_NODES; r0 += AGG_BLOCKS * 4 * 2) {
        const int r1 = r0 + 1;
        int d0 = deg[r0]; if (d0 > MAX_DEG) d0 = MAX_DEG;
        int d1 = deg[r1]; if (d1 > MAX_DEG) d1 = MAX_DEG;
        const unsigned* p0 = nbr + (size_t)r0 * MAX_DEG;
        const unsigned* p1 = p0 + MAX_DEG;
        float4 A0 = make_float4(0.f, 0.f, 0.f, 0.f);
        float4 A1 = make_float4(0.f, 0.f, 0.f, 0.f);
        const int dmin = d0 < d1 ? d0 : d1;
        int j = 0;
        for (; j + 4 <= dmin; j += 4) {          // 8 independent gathers in flight
            uint4 q0 = *(const uint4*)(p0 + j);
            uint4 q1 = *(const uint4*)(p1 + j);
            ushort4 u00 = *(const ushort4*)(Hb + (size_t)(q0.x & 0xFFFFu) * D + ch);
            ushort4 u01 = *(const ushort4*)(Hb + (size_t)(q0.y & 0xFFFFu) * D + ch);
            ushort4 u02 = *(const ushort4*)(Hb + (size_t)(q0.z & 0xFFFFu) * D + ch);
            ushort4 u03 = *(const ushort4*)(Hb + (size_t)(q0.w & 0xFFFFu) * D + ch);
            ushort4 u10 = *(const ushort4*)(Hb + (size_t)(q1.x & 0xFFFFu) * D + ch);
            ushort4 u11 = *(const ushort4*)(Hb + (size_t)(q1.y & 0xFFFFu) * D + ch);
            ushort4 u12 = *(const ushort4*)(Hb + (size_t)(q1.z & 0xFFFFu) * D + ch);
            ushort4 u13 = *(const ushort4*)(Hb + (size_t)(q1.w & 0xFFFFu) * D + ch);
            float w;
            w = bf2f((unsigned short)(q0.x >> 16));
            A0.x = fmaf(w, bf2f(u00.x), A0.x); A0.y = fmaf(w, bf2f(u00.y), A0.y);
            A0.z = fmaf(w, bf2f(u00.z), A0.z); A0.w = fmaf(w, bf2f(u00.w), A0.w);
            w = bf2f((unsigned short)(q0.y >> 16));
            A0.x = fmaf(w, bf2f(u01.x), A0.x); A0.y = fmaf(w, bf2f(u01.y), A0.y);
            A0.z = fmaf(w, bf2f(u01.z), A0.z); A0.w = fmaf(w, bf2f(u01.w), A0.w);
            w = bf2f((unsigned short)(q0.z >> 16));
            A0.x = fmaf(w, bf2f(u02.x), A0.x); A0.y = fmaf(w, bf2f(u02.y), A0.y);
            A0.z = fmaf(w, bf2f(u02.z), A0.z); A0.w = fmaf(w, bf2f(u02.w), A0.w);
            w = bf2f((unsigned short)(q0.w >> 16));
            A0.x = fmaf(w, bf2f(u03.x), A0.x); A0.y = fmaf(w, bf2f(u03.y), A0.y);
            A0.z = fmaf(w, bf2f(u03.z), A0.z); A0.w = fmaf(w, bf2f(u03.w), A0.w);
            w = bf2f((unsigned short)(q1.x >> 16));
            A1.x = fmaf(w, bf2f(u10.x), A1.x); A1.y = fmaf(w, bf2f(u10.y), A1.y);
            A1.z = fmaf(w, bf2f(u10.z), A1.z); A1.w = fmaf(w, bf2f(u10.w), A1.w);
            w = bf2f((unsigned short)(q1.y >> 16));
            A1.x = fmaf(w, bf2f(u11.x), A1.x); A1.y = fmaf(w, bf2f(u11.y), A1.y);
            A1.z = fmaf(w, bf2f(u11.z), A1.z); A1.w = fmaf(w, bf2f(u11.w), A1.w);
            w = bf2f((unsigned short)(q1.z >> 16));
            A1.x = fmaf(w, bf2f(u12.x), A1.x); A1.y = fmaf(w, bf2f(u12.y), A1.y);
            A1.z = fmaf(w, bf2f(u12.z), A1.z); A1.w = fmaf(w, bf2f(u12.w), A1.w);
            w = bf2f((unsigned short)(q1.w >> 16));
            A1.x = fmaf(w, bf2f(u13.x), A1.x); A1.y = fmaf(w, bf2f(u13.y), A1.y);
            A1.z = fmaf(w, bf2f(u13.z), A1.z); A1.w = fmaf(w, bf2f(u13.w), A1.w);
        }
        // row-0 remainder (4-wide then scalar)
        int j0 = j;
        for (; j0 + 4 <= d0; j0 += 4) {
            uint4 q0 = *(const uint4*)(p0 + j0);
            ushort4 u0 = *(const ushort4*)(Hb + (size_t)(q0.x & 0xFFFFu) * D + ch);
            ushort4 u1 = *(const ushort4*)(Hb + (size_t)(q0.y & 0xFFFFu) * D + ch);
            ushort4 u2 = *(const ushort4*)(Hb + (size_t)(q0.z & 0xFFFFu) * D + ch);
            ushort4 u3 = *(const ushort4*)(Hb + (size_t)(q0.w & 0xFFFFu) * D + ch);
            float w;
            w = bf2f((unsigned short)(q0.x >> 16));
            A0.x = fmaf(w, bf2f(u0.x), A0.x); A0.y = fmaf(w, bf2f(u0.y), A0.y);
            A0.z = fmaf(w, bf2f(u0.z), A0.z); A0.w = fmaf(w, bf2f(u0.w), A0.w);
            w = bf2f((unsigned short)(q0.y >> 16));
            A0.x = fmaf(w, bf2f(u1.x), A0.x); A0.y = fmaf(w, bf2f(u1.y), A0.y);
            A0.z = fmaf(w, bf2f(u1.z), A0.z); A0.w = fmaf(w, bf2f(u1.w), A0.w);
            w = bf2f((unsigned short)(q0.z >> 16));
            A0.x = fmaf(w, bf2f(u2.x), A0.x); A0.y = fmaf(w, bf2f(u2.y), A0.y);
            A0.z = fmaf(w, bf2f(u2.z), A0.z); A0.w = fmaf(w, bf2f(u2.w), A0.w);
            w = bf2f((unsigned short)(q0.w >> 16));
            A0.x = fmaf(w, bf2f(u3.x), A0.x); A0.y = fmaf(w, bf2f(u3.y), A0.y);
            A0.z = fmaf(w, bf2f(u3.z), A0.z); A0.w = fmaf(w, bf2f(u3.w), A0.w);
        }
        for (; j0 < d0; j0++) {
            unsigned qv = p0[j0];
            float w = bf2f((unsigned short)(qv >> 16));
            ushort4 u = *(const ushort4*)(Hb + (size_t)(qv & 0xFFFFu) * D + ch);
            A0.x = fmaf(w, bf2f(u.x), A0.x); A0.y = fmaf(w, bf2f(u.y), A0.y);
            A0.z = fmaf(w, bf2f(u.z), A0.z); A0.w = fmaf(w, bf2f(u.w), A0.w);
        }
        // row-1 remainder
        int j1 = j;
        for (; j1 + 4 <= d1; j1 += 4) {
            uint4 q1 = *(const uint4*)(p1 + j1);
            ushort4 u0 = *(const ushort4*)(Hb + (size_t)(q1.x & 0xFFFFu) * D + ch);
            ushort4 u1 = *(const ushort4*)(Hb + (size_t)(q1.y & 0xFFFFu) * D + ch);
            ushort4 u2 = *(const ushort4*)(Hb + (size_t)(q1.z & 0xFFFFu) * D + ch);
            ushort4 u3 = *(const ushort4*)(Hb + (size_t)(q1.w & 0xFFFFu) * D + ch);
            float w;
            w = bf2f((unsigned short)(q1.x >> 16));
            A1.x = fmaf(w, bf2f(u0.x), A1.x); A1.y = fmaf(w, bf2f(u0.y), A1.y);
            A1.z = fmaf(w, bf2f(u0.z), A1.z); A1.w = fmaf(w, bf2f(u0.w), A1.w);
            w = bf2f((unsigned short)(q1.y >> 16));
            A1.x = fmaf(w, bf2f(u1.x), A1.x); A1.y = fmaf(w, bf2f(u1.y), A1.y);
            A1.z = fmaf(w, bf2f(u1.z), A1.z); A1.w = fmaf(w, bf2f(u1.w), A1.w);
            w = bf2f((unsigned short)(q1.z >> 16));
            A1.x = fmaf(w, bf2f(u2.x), A1.x); A1.y = fmaf(w, bf2f(u2.y), A1.y);
            A1.z = fmaf(w, bf2f(u2.z), A1.z); A1.w = fmaf(w, bf2f(u2.w), A1.w);
            w = bf2f((unsigned short)(q1.w >> 16));
            A1.x = fmaf(w, bf2f(u3.x), A1.x); A1.y = fmaf(w, bf2f(u3.y), A1.y);
            A1.z = fmaf(w, bf2f(u3.z), A1.z); A1.w = fmaf(w, bf2f(u3.w), A1.w);
        }
        for (; j1 < d1; j1++) {
            unsigned qv = p1[j1];
            float w = bf2f((unsigned short)(qv >> 16));
            ushort4 u = *(const ushort4*)(Hb + (size_t)(qv & 0xFFFFu) * D + ch);
            A1.x = fmaf(w, bf2f(u.x), A1.x); A1.y = fmaf(w, bf2f(u.y), A1.y);
            A1.z = fmaf(w, bf2f(u.z), A1.z); A1.w = fmaf(w, bf2f(u.w), A1.w);
        }
        *(float4*)(G + (size_t)r0 * D + ch) = A0;
        *(float4*)(G + (size_t)r1 * D + ch) = A1;
        sp[0] += A0.x + A1.x; sp[1] += A0.y + A1.y;
        sp[2] += A0.z + A1.z; sp[3] += A0.w + A1.w;
        ssp[0] += A0.x * A0.x + A1.x * A1.x; ssp[1] += A0.y * A0.y + A1.y * A1.y;
        ssp[2] += A0.z * A0.z + A1.z * A1.z; ssp[3] += A0.w * A0.w + A1.w * A1.w;
    }

    __shared__ float ls[4][256], lss[4][256];
    #pragma unroll
    for (int c = 0; c < 4; c++) {
        ls[wave][ch + c] = sp[c];
        lss[wave][ch + c] = ssp[c];
    }
    __syncthreads();
    const int t = threadIdx.x;
    psum[blockIdx.x * 256 + t] = ls[0][t] + ls[1][t] + ls[2][t] + ls[3][t];
    psumsq[blockIdx.x * 256 + t] = lss[0][t] + lss[1][t] + lss[2][t] + lss[3][t];
}

// ---------------- BN stats finalize: scale/shift (1024 threads, coalesced) ----------------
__global__ __launch_bounds__(1024) void bn_stats2(const float* __restrict__ psum,
                                                  const float* __restrict__ psumsq,
                                                  const float* __restrict__ g,
                                                  const float* __restrict__ be,
                                                  float* __restrict__ scale,
                                                  float* __restrict__ shift) {
    const int t = threadIdx.x;
    const int chn = t & 255, part = t >> 8;   // 4 partitions per channel
    float s = 0.0f, q = 0.0f;
    for (int i = part; i < AGG_BLOCKS; i += 4) {
        s += psum[i * 256 + chn];
        q += psumsq[i * 256 + chn];
    }
    __shared__ float as[4][256], aq[4][256];
    as[part][chn] = s;
    aq[part][chn] = q;
    __syncthreads();
    if (t < 256) {
        s = as[0][t] + as[1][t] + as[2][t] + as[3][t];
        q = aq[0][t] + aq[1][t] + aq[2][t] + aq[3][t];
        float mu = s * (1.0f / N_NODES);
        float var = q * (1.0f / N_NODES) - mu * mu;
        float rstd = rsqrtf(var + 1e-5f);
        float sc = g[t] * rstd;
        scale[t] = sc;
        shift[t] = be[t] - mu * sc;
    }
}

// ---------------- final BN apply -> fp32 d_out (no relu) ----------------
__global__ __launch_bounds__(256) void bn_apply_out(const float* __restrict__ G,
                                                    const float* __restrict__ scale,
                                                    const float* __restrict__ shift,
                                                    float* __restrict__ Out) {
    int i = (blockIdx.x * 256 + threadIdx.x) * 4;
    int d = i & (D - 1);
    float4 v = *(const float4*)(G + i);
    float4 sc = *(const float4*)(scale + d);
    float4 sh = *(const float4*)(shift + d);
    v.x = fmaf(v.x, sc.x, sh.x);
    v.y = fmaf(v.y, sc.y, sh.y);
    v.z = fmaf(v.z, sc.z, sh.z);
    v.w = fmaf(v.w, sc.w, sh.w);
    *(float4*)(Out + i) = v;
}

extern "C" void kernel_launch(void* const* d_in, const int* in_sizes, int n_in,
                              void* d_out, int out_size, void* d_ws, size_t ws_size,
                              hipStream_t stream) {
    const float* x  = (const float*)d_in[0];
    const int*   ei = (const int*)d_in[1];
    const float* W1 = (const float*)d_in[2];
    const float* b1 = (const float*)d_in[3];
    const float* W2 = (const float*)d_in[4];
    const float* b2 = (const float*)d_in[5];
    const float* W3 = (const float*)d_in[6];
    const float* b3 = (const float*)d_in[7];
    const float* g1 = (const float*)d_in[8];
    const float* be1 = (const float*)d_in[9];
    const float* g2 = (const float*)d_in[10];
    const float* be2 = (const float*)d_in[11];
    const float* g3 = (const float*)d_in[12];
    const float* be3 = (const float*)d_in[13];

    char* ws = (char*)d_ws;
    // [0, 8MB): adj bitmask; dead after build_nbrs -> reused as Hb (bf16, 4 MB)
    unsigned*       adj  = (unsigned*)ws;
    unsigned short* Hb   = (unsigned short*)ws;                     // 4 MB
    int*            deg  = (int*)(ws + (8 << 20));                  // 32 KB (zeroed w/ adj)
    float*          dinv = (float*)(ws + (8 << 20) + (32 << 10));   // 32 KB
    float*          scale= (float*)(ws + (8 << 20) + (64 << 10));   // 1 KB
    float*          shift= (float*)(ws + (8 << 20) + (68 << 10));   // 1 KB
    unsigned short* Wb1  = (unsigned short*)(ws + (8 << 20) + (128 << 10));
    unsigned short* Wb2  = (unsigned short*)(ws + (8 << 20) + (256 << 10));
    unsigned short* Wb3  = (unsigned short*)(ws + (8 << 20) + (384 << 10));
    float*          psum = (float*)(ws + (9 << 20));                // 512 KB
    float*          psq  = (float*)(ws + (9 << 20) + (512 << 10));  // 512 KB
    unsigned*       nbr  = (unsigned*)(ws + (10 << 20));            // 4 MB packed
    float*          G    = (float*)(ws + (14 << 20));               // 8 MB

    // zero adj + deg in one fill
    hipMemsetAsync(ws, 0, (8 << 20) + (32 << 10), stream);

    build_adj<<<(N_EDGES + N_NODES + 255) / 256, 256, 0, stream>>>(ei, adj, deg);
    compute_dinv<<<N_NODES / 256, 256, 0, stream>>>(deg, dinv);
    build_nbrs<<<N_NODES + 768, 256, 0, stream>>>(adj, dinv, nbr,
                                                  W1, W2, W3, Wb1, Wb2, Wb3);

    dim3 ggrid(D / 64, N_NODES / 128);

    // ---- Layer 1
    gemm_mfma<false, false><<<ggrid, 256, 0, stream>>>(x, nullptr, nullptr, Wb1, b1, Hb);
    aggregate_bf16<<<AGG_BLOCKS, 256, 0, stream>>>(nbr, deg, Hb, G, psum, psq);
    bn_stats2<<<1, 1024, 0, stream>>>(psum, psq, g1, be1, scale, shift);

    // ---- Layer 2 (bn+relu fused into gemm X-load)
    gemm_mfma<true, true><<<ggrid, 256, 0, stream>>>(G, scale, shift, Wb2, b2, Hb);
    aggregate_bf16<<<AGG_BLOCKS, 256, 0, stream>>>(nbr, deg, Hb, G, psum, psq);
    bn_stats2<<<1, 1024, 0, stream>>>(psum, psq, g2, be2, scale, shift);

    // ---- Layer 3
    gemm_mfma<true, true><<<ggrid, 256, 0, stream>>>(G, scale, shift, Wb3, b3, Hb);
    aggregate_bf16<<<AGG_BLOCKS, 256, 0, stream>>>(nbr, deg, Hb, G, psum, psq);
    bn_stats2<<<1, 1024, 0, stream>>>(psum, psq, g3, be3, scale, shift);

    // ---- final BN apply -> d_out
    bn_apply_out<<<N_NODES * D / 1024, 256, 0, stream>>>(G, scale, shift, (float*)d_out);
}